// Round 11
// baseline (457.991 us; speedup 1.0000x reference)
//
#include <hip/hip_runtime.h>
#include <hip/hip_bf16.h>

// ---------------------------------------------------------------------------
// Round 11 (= round 8 resubmitted; 3rd attempt): k_l0m full-N (256) +
// K-split-8 + atomicAdd partials (fixes grid-limited 2-blocks/CU occupancy
// from r7: MfmaUtil 16%, Occ 21%). Merged prologue (k_zero3 + k_prep).
// ---------------------------------------------------------------------------

constexpr int BB = 2, QQ = 4096, DIMC = 192, RAW = 49;
constexpr int ENC = 64, P1 = 66, P3 = 70;

typedef __attribute__((ext_vector_type(8))) short bf16x8;
typedef __attribute__((ext_vector_type(8))) unsigned short u16x8;
typedef __attribute__((ext_vector_type(4))) float f32x4;

__device__ inline short f2bf(float f) {
  __hip_bfloat16 h = __float2bfloat16(f);
  return __builtin_bit_cast(short, h);
}
__device__ inline float bf2f(unsigned short u) {
  return __uint_as_float(((unsigned)u) << 16);
}

// ---- ws layout (float units) ----
constexpr long long F_F1 = 0;                 // f1p bf16: 557568 sh
constexpr long long F_FEAT = 278784;          // featp bf16: 1672704 sh
constexpr long long F_FQ = 1115136;           // featqp f32: 1672704 f
constexpr long long ZA_END = 2787840;
constexpr long long F_FKB = 4194304;          // fkb bf16: 1881600 sh
constexpr long long F_FVB = 5135104;          // fvb bf16
constexpr long long F_ATTN = 6075904;         // attnb bf16
constexpr long long F_W0T = 7681536;          // w0t bf16 [256][9408]
constexpr long long F_WTCH = 8885760;
constexpr long long F_WTQ = 8941056;
constexpr long long F_WTK = 9106944;
constexpr long long F_WTV = 9272832;
constexpr long long F_WFC1 = 9438720;
constexpr long long F_WFC2 = 9471488;
constexpr long long F_WFC3 = 9504256;
constexpr long long F_HA = 9537024;           // h bf16
constexpr long long F_HB = 10585600;
constexpr long long F_PART = 11634176;        // 8192*256 f32 atomic buffer
// end = 13731328 f = 54.9 MB

// zero three spans: zone A, fkb+fvb, part
__global__ __launch_bounds__(256) void k_zero3(float4* ws4) {
  const int a4 = (int)(ZA_END / 4);            // 696960
  const int b4 = 470400;                       // (fkb+fvb) floats /4
  const int c4 = 524288;                       // part /4
  int n4 = a4 + b4 + c4;
  float4 z = make_float4(0.f, 0.f, 0.f, 0.f);
  for (int i = blockIdx.x * 256 + threadIdx.x; i < n4; i += gridDim.x * 256) {
    float4* p;
    if (i < a4) p = ws4 + i;
    else if (i < a4 + b4) p = ws4 + (int)(F_FKB / 4) + (i - a4);
    else p = ws4 + (int)(F_PART / 4) + (i - a4 - b4);
    *p = z;
  }
}

// merged weight prep: w0t transpose + conv wtb x4 + fc wt x3
__global__ __launch_bounds__(256) void k_prep(
    const float* __restrict__ m0w, const float* __restrict__ ch_w,
    const float* __restrict__ q_w, const float* __restrict__ k_w,
    const float* __restrict__ v_w, const float* __restrict__ m1w,
    const float* __restrict__ m2w, const float* __restrict__ m3w,
    short* __restrict__ w0t, short* __restrict__ wtb_ch, short* __restrict__ wtb_q,
    short* __restrict__ wtb_k, short* __restrict__ wtb_v, short* __restrict__ wfc1,
    short* __restrict__ wfc2, short* __restrict__ wfc3) {
  __shared__ short sh[64][72];
  int bb = blockIdx.x, t = threadIdx.x;
  if (bb < 588) {  // w0t [9410][256] -> [256][9408]
    int k0 = (bb % 147) * 64, n0 = (bb / 147) * 64;
    #pragma unroll
    for (int i = 0; i < 16; i++) {
      int idx = t + i * 256;
      int r = idx >> 6, cc = idx & 63;
      sh[cc][r] = f2bf(m0w[(long long)(k0 + r) * 256 + n0 + cc]);
    }
    __syncthreads();
    #pragma unroll
    for (int i = 0; i < 16; i++) {
      int idx = t + i * 256;
      int n = idx >> 6, k = idx & 63;
      w0t[(long long)(n0 + n) * 9408 + k0 + k] = sh[n][k];
    }
    return;
  }
  const float* src = nullptr;
  short* dst = nullptr;
  int CI = 0, base = 0;
  if (bb < 1020) { src = ch_w; dst = wtb_ch; CI = 64; base = 588; }
  else if (bb < 2316) { src = q_w; dst = wtb_q; CI = 192; base = 1020; }
  else if (bb < 3612) { src = k_w; dst = wtb_k; CI = 192; base = 2316; }
  else if (bb < 4908) { src = v_w; dst = wtb_v; CI = 192; base = 3612; }
  if (dst) {  // w [192][CI][3][3] -> [192][9*CI], k = tap*CI+ci
    int g = (bb - base) * 256 + t;
    if (g < 192 * CI * 9) {
      int co = g / (CI * 9);
      int r = g - co * CI * 9;
      int ci = r / 9, tp = r - ci * 9;
      dst[(long long)co * (9 * CI) + tp * CI + ci] = f2bf(src[g]);
    }
    return;
  }
  const float* fsrc; short* fdst; int n;
  if (bb < 5164) { fsrc = m1w; fdst = wfc1; n = bb - 4908; }
  else if (bb < 5420) { fsrc = m2w; fdst = wfc2; n = bb - 5164; }
  else { fsrc = m3w; fdst = wfc3; n = bb - 5420; }
  fdst[n * 256 + t] = f2bf(fsrc[t * 256 + n]);
}

// inp [B][3][64][64] fp32 -> f1p [B][66][66][64] bf16 interior
__global__ __launch_bounds__(256) void k_conv1(const float* __restrict__ inp,
                                               const float* __restrict__ ew,
                                               const float* __restrict__ eb,
                                               unsigned short* __restrict__ f1p) {
  int g = blockIdx.x * 256 + threadIdx.x;
  int co = g & 63, x = (g >> 6) & 63, y = (g >> 12) & 63, b = g >> 18;
  float acc = eb[co];
  #pragma unroll
  for (int ci = 0; ci < 3; ci++)
    #pragma unroll
    for (int ky = 0; ky < 3; ky++) {
      int yy = y + ky - 1;
      if (yy < 0 || yy > 63) continue;
      #pragma unroll
      for (int kx = 0; kx < 3; kx++) {
        int xx = x + kx - 1;
        if (xx < 0 || xx > 63) continue;
        acc += inp[((b * 3 + ci) * 64 + yy) * 64 + xx] * ew[((co * 3 + ci) * 3 + ky) * 3 + kx];
      }
    }
  f1p[((b * P1 + y + 1) * P1 + (x + 1)) * ENC + co] = (unsigned short)f2bf(acc);
}

// MFMA 3x3 conv: in bf16 [B][66][66][CIN]; wtb [192][9*CIN] bf16.
template <int CIN, bool OF32>
__global__ __launch_bounds__(256) void k_conv3x3m(const unsigned short* __restrict__ in,
                                                  const short* __restrict__ wtb,
                                                  const float* __restrict__ bias,
                                                  void* __restrict__ outv, int pitchO,
                                                  int padO) {
  constexpr int NCH = CIN / 64;
  int nb = blockIdx.x;
  int by = blockIdx.y;
  int b = by >> 6, y = by & 63;
  int t = threadIdx.x;
  int lane = t & 63, w = t >> 6, wr = w >> 1, wc = w & 1;
  __shared__ __align__(16) short As[64][72];
  __shared__ __align__(16) short Bs[64][72];
  f32x4 acc[2][2];
  #pragma unroll
  for (int i = 0; i < 2; i++)
    #pragma unroll
    for (int j = 0; j < 2; j++) acc[i][j] = (f32x4){0.f, 0.f, 0.f, 0.f};
  int arow = t >> 2, kq4 = t & 3;
  int nbase = nb * 64;
  const long long K9 = 9LL * CIN;
  for (int c = 0; c < 9 * NCH; c++) {
    int t9 = c / NCH, sub = c - t9 * NCH;
    int dy = t9 / 3 - 1, dx = t9 % 3 - 1;
    __syncthreads();
    {
      const unsigned short* src = in +
          (((long long)b * P1 + y + dy + 1) * P1 + (arow + dx + 1)) * CIN + sub * 64 + kq4 * 16;
      *(bf16x8*)&As[arow][kq4 * 16] = *(const bf16x8*)src;
      *(bf16x8*)&As[arow][kq4 * 16 + 8] = *(const bf16x8*)(src + 8);
      const short* wp = wtb + (long long)(nbase + arow) * K9 + c * 64 + kq4 * 16;
      *(bf16x8*)&Bs[arow][kq4 * 16] = *(const bf16x8*)wp;
      *(bf16x8*)&Bs[arow][kq4 * 16 + 8] = *(const bf16x8*)(wp + 8);
    }
    __syncthreads();
    #pragma unroll
    for (int kk = 0; kk < 2; kk++) {
      bf16x8 a0 = *(const bf16x8*)&As[wr * 32 + (lane & 15)][kk * 32 + (lane >> 4) * 8];
      bf16x8 a1 = *(const bf16x8*)&As[wr * 32 + 16 + (lane & 15)][kk * 32 + (lane >> 4) * 8];
      bf16x8 b0 = *(const bf16x8*)&Bs[wc * 32 + (lane & 15)][kk * 32 + (lane >> 4) * 8];
      bf16x8 b1 = *(const bf16x8*)&Bs[wc * 32 + 16 + (lane & 15)][kk * 32 + (lane >> 4) * 8];
      acc[0][0] = __builtin_amdgcn_mfma_f32_16x16x32_bf16(a0, b0, acc[0][0], 0, 0, 0);
      acc[0][1] = __builtin_amdgcn_mfma_f32_16x16x32_bf16(a0, b1, acc[0][1], 0, 0, 0);
      acc[1][0] = __builtin_amdgcn_mfma_f32_16x16x32_bf16(a1, b0, acc[1][0], 0, 0, 0);
      acc[1][1] = __builtin_amdgcn_mfma_f32_16x16x32_bf16(a1, b1, acc[1][1], 0, 0, 0);
    }
  }
  int col0 = nbase + wc * 32 + (lane & 15);
  int row0 = wr * 32 + ((lane >> 4) << 2);
  #pragma unroll
  for (int nf = 0; nf < 2; nf++) {
    int co = col0 + nf * 16;
    float bv = bias[co];
    #pragma unroll
    for (int mf = 0; mf < 2; mf++)
      #pragma unroll
      for (int i = 0; i < 4; i++) {
        int x = row0 + mf * 16 + i;
        long long oi = (((long long)b * pitchO + y + padO) * pitchO + (x + padO)) * DIMC + co;
        float val = acc[mf][nf][i] + bv;
        if (OF32) ((float*)outv)[oi] = val;
        else ((unsigned short*)outv)[oi] = (unsigned short)f2bf(val);
      }
  }
}

// per-query attention probs -> attnb bf16 [bq][49][8]
__global__ __launch_bounds__(64) void k_attn(const float* __restrict__ sc,
                                             const float* __restrict__ fq,
                                             const unsigned short* __restrict__ fkb,
                                             unsigned short* __restrict__ attnO) {
  int bq = blockIdx.x;
  int b = bq >> 12;
  int lane = threadIdx.x;
  float cy = sc[bq * 2 + 0], cx = sc[bq * 2 + 1];
  float py = (cy + 1.f) * 32.f - 0.5f, px = (cx + 1.f) * 32.f - 0.5f;
  float fy = floorf(py), fx = floorf(px);
  float wy = py - fy, wx = px - fx;
  int iy = (int)fy, ix = (int)fx;
  __shared__ __align__(16) float qv[192];
  {
    const float* base = fq + (((long long)b * P1 + iy + 1) * P1 + (ix + 1)) * DIMC;
    #pragma unroll
    for (int u = 0; u < 3; u++) {
      int c = lane * 3 + u;
      float v00 = base[c], v01 = base[DIMC + c];
      float v10 = base[P1 * DIMC + c], v11 = base[P1 * DIMC + DIMC + c];
      qv[c] = (1.f - wy) * ((1.f - wx) * v00 + wx * v01) +
              wy * ((1.f - wx) * v10 + wx * v11);
    }
  }
  __syncthreads();
  int icy = min(max((int)floorf(py + 0.5f), 0), 63);
  int icx = min(max((int)floorf(px + 0.5f), 0), 63);
  float l[8];
  #pragma unroll
  for (int h = 0; h < 8; h++) l[h] = -1e30f;
  if (lane < 49) {
    int dy = lane / 7 - 3, dx = lane % 7 - 3;
    const unsigned short* kb =
        fkb + (((long long)b * P3 + icy + dy + 3) * P3 + (icx + dx + 3)) * DIMC;
    #pragma unroll
    for (int h = 0; h < 8; h++) l[h] = 0.f;
    #pragma unroll
    for (int c8 = 0; c8 < 24; c8++) {
      u16x8 k8 = *(const u16x8*)(kb + c8 * 8);
      float4 qa = *(const float4*)&qv[c8 * 8];
      float4 qb = *(const float4*)&qv[c8 * 8 + 4];
      l[c8 / 3] += qa.x * bf2f(k8[0]) + qa.y * bf2f(k8[1]) + qa.z * bf2f(k8[2]) +
                   qa.w * bf2f(k8[3]) + qb.x * bf2f(k8[4]) + qb.y * bf2f(k8[5]) +
                   qb.z * bf2f(k8[6]) + qb.w * bf2f(k8[7]);
    }
    const float s = 0.20412414523193154f;  // 1/sqrt(24)
    #pragma unroll
    for (int h = 0; h < 8; h++) l[h] *= s;
  }
  bf16x8 a8;
  #pragma unroll
  for (int h = 0; h < 8; h++) {
    float mx = l[h];
    #pragma unroll
    for (int s = 1; s < 64; s <<= 1) mx = fmaxf(mx, __shfl_xor(mx, s));
    float e = (lane < 49) ? expf(l[h] - mx) : 0.f;
    float sm = e;
    #pragma unroll
    for (int s = 1; s < 64; s <<= 1) sm += __shfl_xor(sm, s);
    a8[h] = f2bf(e / sm);
  }
  if (lane < 49) {
    *(bf16x8*)(attnO + ((long long)bq * 49 + lane) * 8) = a8;
  }
}

// fused gather+attn+GEMM: full N=256, K-split 8 (bx -> XCD), atomicAdd partials
__global__ __launch_bounds__(256) void k_l0m(const float* __restrict__ sc,
                                             const unsigned short* __restrict__ fvb,
                                             const unsigned short* __restrict__ attn,
                                             const short* __restrict__ w0t,
                                             float* __restrict__ part) {
  int kq = blockIdx.x;    // 0..7 K-slice, maps to XCD (x-fastest dispatch)
  int mb = blockIdx.y;    // 0..127
  int qbase = mb * 64;
  int b = mb >> 6;
  int t = threadIdx.x;
  int lane = t & 63, w = t >> 6, wr = w >> 1, wc = w & 1;
  __shared__ __align__(16) short As[64][72];
  __shared__ __align__(16) short Bs[256][72];
  int arow = t >> 2, kq4 = t & 3;
  int q = qbase + arow;
  float cy = sc[q * 2 + 0], cx = sc[q * 2 + 1];
  float py = (cy + 1.f) * 32.f - 0.5f, px = (cx + 1.f) * 32.f - 0.5f;
  int icy = min(max((int)floorf(py + 0.5f), 0), 63);
  int icx = min(max((int)floorf(px + 0.5f), 0), 63);
  const unsigned short* fvp = fvb + (((long long)b * P3 + icy + 3) * P3 + (icx + 3)) * DIMC;
  const unsigned short* ap = attn + (long long)q * 392;
  int ch0 = kq4 * 16;
  f32x4 acc[2][8];
  #pragma unroll
  for (int i = 0; i < 2; i++)
    #pragma unroll
    for (int j = 0; j < 8; j++) acc[i][j] = (f32x4){0.f, 0.f, 0.f, 0.f};
  int c0 = kq * 18 + min(kq, 3);
  int cnt = 18 + (kq < 3 ? 1 : 0);
  for (int ci = 0; ci < cnt; ci++) {
    int cc = c0 + ci;
    int r = cc / 3, sub = cc - r * 3;
    int dy2 = r / 7 - 3, dx2 = r % 7 - 3;
    long long tap = ((long long)dy2 * P3 + dx2) * DIMC;
    __syncthreads();
    {
      // A: V-gather + attn weight -> bf16 (64 q-rows x 64 ch)
      const unsigned short* src = fvp + tap + sub * 64 + ch0;
      u16x8 r0 = *(const u16x8*)src;
      u16x8 r1 = *(const u16x8*)(src + 8);
      int cA = sub * 64 + ch0;
      float a0 = bf2f(ap[r * 8 + cA / 24]);
      float a1 = bf2f(ap[r * 8 + (cA + 8) / 24]);
      bf16x8 pk0, pk1;
      #pragma unroll
      for (int e = 0; e < 8; e++) pk0[e] = f2bf(bf2f(r0[e]) * a0);
      #pragma unroll
      for (int e = 0; e < 8; e++) pk1[e] = f2bf(bf2f(r1[e]) * a1);
      *(bf16x8*)&As[arow][ch0] = pk0;
      *(bf16x8*)&As[arow][ch0 + 8] = pk1;
      // B: all 256 w0t rows, 64-ch k-chunk; thread t stages row t
      const short* wp = w0t + (long long)t * 9408 + cc * 64;
      #pragma unroll
      for (int j = 0; j < 8; j++)
        *(bf16x8*)&Bs[t][j * 8] = *(const bf16x8*)(wp + j * 8);
    }
    __syncthreads();
    #pragma unroll
    for (int kk = 0; kk < 2; kk++) {
      bf16x8 av0 = *(const bf16x8*)&As[wr * 32 + (lane & 15)][kk * 32 + (lane >> 4) * 8];
      bf16x8 av1 = *(const bf16x8*)&As[wr * 32 + 16 + (lane & 15)][kk * 32 + (lane >> 4) * 8];
      #pragma unroll
      for (int nf = 0; nf < 8; nf++) {
        bf16x8 bv = *(const bf16x8*)&Bs[wc * 128 + nf * 16 + (lane & 15)][kk * 32 + (lane >> 4) * 8];
        acc[0][nf] = __builtin_amdgcn_mfma_f32_16x16x32_bf16(av0, bv, acc[0][nf], 0, 0, 0);
        acc[1][nf] = __builtin_amdgcn_mfma_f32_16x16x32_bf16(av1, bv, acc[1][nf], 0, 0, 0);
      }
    }
  }
  int row0 = wr * 32 + ((lane >> 4) << 2);
  int colb = wc * 128 + (lane & 15);
  #pragma unroll
  for (int mf = 0; mf < 2; mf++)
    #pragma unroll
    for (int nf = 0; nf < 8; nf++)
      #pragma unroll
      for (int i = 0; i < 4; i++)
        atomicAdd(&part[(long long)(qbase + row0 + mf * 16 + i) * 256 + colb + nf * 16],
                  acc[mf][nf][i]);
}

// part + tail + relu -> h bf16
__global__ __launch_bounds__(256) void k_l0red(const float* __restrict__ part,
                                               const float* __restrict__ cell,
                                               const float* __restrict__ w0,
                                               const float* __restrict__ b0,
                                               unsigned short* __restrict__ h) {
  int gid = blockIdx.x * 256 + threadIdx.x;
  int q = gid >> 6, n0 = (gid & 63) << 2;
  int b = q >> 12;
  float rc0 = cell[b * 2 + 0] * 64.f, rc1 = cell[b * 2 + 1] * 64.f;
  float4 s0 = ((const float4*)part)[gid];
  unsigned short o[4];
  #pragma unroll
  for (int j = 0; j < 4; j++) {
    int n = n0 + j;
    float tailv = rc0 * w0[9408LL * 256 + n] + rc1 * w0[9409LL * 256 + n] + b0[n];
    float v = ((const float*)&s0)[j] + tailv;
    o[j] = (unsigned short)f2bf(fmaxf(v, 0.f));
  }
  *(uint2*)(h + (long long)gid * 4) = *(uint2*)o;
}

// fc: h_out = relu(h_in[8192,256]bf16 @ wt[n][k]bf16 + bias), out bf16
__global__ __launch_bounds__(256) void k_fcm(const unsigned short* __restrict__ hin,
                                             const short* __restrict__ wt,
                                             const float* __restrict__ bias,
                                             unsigned short* __restrict__ hout) {
  int nb = blockIdx.x, mb = blockIdx.y;
  int qbase = mb * 64, nbase = nb * 64;
  int t = threadIdx.x;
  int lane = t & 63, w = t >> 6, wr = w >> 1, wc = w & 1;
  __shared__ __align__(16) short As[64][264];
  __shared__ __align__(16) short Bs[64][264];
  int row = t >> 2, seg = t & 3;
  {
    const unsigned short* hp = hin + (long long)(qbase + row) * 256 + seg * 64;
    const short* wp = wt + (long long)(nbase + row) * 256 + seg * 64;
    #pragma unroll
    for (int j = 0; j < 8; j++) {
      *(bf16x8*)&As[row][seg * 64 + j * 8] = *(const bf16x8*)(hp + j * 8);
      *(bf16x8*)&Bs[row][seg * 64 + j * 8] = *(const bf16x8*)(wp + j * 8);
    }
  }
  __syncthreads();
  f32x4 acc[2][2];
  #pragma unroll
  for (int i = 0; i < 2; i++)
    #pragma unroll
    for (int j = 0; j < 2; j++) acc[i][j] = (f32x4){0.f, 0.f, 0.f, 0.f};
  #pragma unroll
  for (int kk = 0; kk < 8; kk++) {
    bf16x8 a0 = *(const bf16x8*)&As[wr * 32 + (lane & 15)][kk * 32 + (lane >> 4) * 8];
    bf16x8 a1 = *(const bf16x8*)&As[wr * 32 + 16 + (lane & 15)][kk * 32 + (lane >> 4) * 8];
    bf16x8 b0 = *(const bf16x8*)&Bs[wc * 32 + (lane & 15)][kk * 32 + (lane >> 4) * 8];
    bf16x8 b1 = *(const bf16x8*)&Bs[wc * 32 + 16 + (lane & 15)][kk * 32 + (lane >> 4) * 8];
    acc[0][0] = __builtin_amdgcn_mfma_f32_16x16x32_bf16(a0, b0, acc[0][0], 0, 0, 0);
    acc[0][1] = __builtin_amdgcn_mfma_f32_16x16x32_bf16(a0, b1, acc[0][1], 0, 0, 0);
    acc[1][0] = __builtin_amdgcn_mfma_f32_16x16x32_bf16(a1, b0, acc[1][0], 0, 0, 0);
    acc[1][1] = __builtin_amdgcn_mfma_f32_16x16x32_bf16(a1, b1, acc[1][1], 0, 0, 0);
  }
  int row0 = wr * 32 + ((lane >> 4) << 2);
  int col0 = nbase + wc * 32 + (lane & 15);
  #pragma unroll
  for (int nf = 0; nf < 2; nf++) {
    int n = col0 + nf * 16;
    float bv = bias[n];
    #pragma unroll
    for (int mf = 0; mf < 2; mf++)
      #pragma unroll
      for (int i = 0; i < 4; i++)
        hout[(long long)(qbase + row0 + mf * 16 + i) * 256 + n] =
            (unsigned short)f2bf(fmaxf(acc[mf][nf][i] + bv, 0.f));
  }
}

// out = h3(bf16) @ m4w + m4b + bilinear(inp, border=True)
__global__ __launch_bounds__(64) void k_final(const unsigned short* __restrict__ h3,
                                              const float* __restrict__ w4,
                                              const float* __restrict__ b4,
                                              const float* __restrict__ sc,
                                              const float* __restrict__ inp,
                                              float* __restrict__ out) {
  int bq = blockIdx.x;
  int b = bq >> 12;
  int lane = threadIdx.x;
  float p0 = 0.f, p1 = 0.f, p2 = 0.f;
  const unsigned short* hr = h3 + (long long)bq * 256;
  #pragma unroll
  for (int u = 0; u < 4; u++) {
    int c = lane + u * 64;
    float hv = bf2f(hr[c]);
    p0 += hv * w4[c * 3 + 0];
    p1 += hv * w4[c * 3 + 1];
    p2 += hv * w4[c * 3 + 2];
  }
  #pragma unroll
  for (int s = 1; s < 64; s <<= 1) {
    p0 += __shfl_xor(p0, s);
    p1 += __shfl_xor(p1, s);
    p2 += __shfl_xor(p2, s);
  }
  if (lane == 0) {
    float cy = sc[bq * 2 + 0], cx = sc[bq * 2 + 1];
    float py = (cy + 1.f) * 32.f - 0.5f, px = (cx + 1.f) * 32.f - 0.5f;
    float fy = floorf(py), fx = floorf(px);
    float wy = py - fy, wx = px - fx;
    int y0 = (int)fy, x0 = (int)fx;
    int yc0 = min(max(y0, 0), 63), yc1 = min(max(y0 + 1, 0), 63);
    int xc0 = min(max(x0, 0), 63), xc1 = min(max(x0 + 1, 0), 63);
    float o[3] = {p0 + b4[0], p1 + b4[1], p2 + b4[2]};
    #pragma unroll
    for (int j = 0; j < 3; j++) {
      const float* im = inp + ((long long)b * 3 + j) * 4096;
      float s00 = im[yc0 * 64 + xc0], s01 = im[yc0 * 64 + xc1];
      float s10 = im[yc1 * 64 + xc0], s11 = im[yc1 * 64 + xc1];
      o[j] += (1.f - wy) * ((1.f - wx) * s00 + wx * s01) +
              wy * ((1.f - wx) * s10 + wx * s11);
      out[(long long)bq * 3 + j] = o[j];
    }
  }
}

extern "C" void kernel_launch(void* const* d_in, const int* in_sizes, int n_in,
                              void* d_out, int out_size, void* d_ws, size_t ws_size,
                              hipStream_t stream) {
  const float* inp = (const float*)d_in[0];
  const float* sc = (const float*)d_in[1];
  const float* cell = (const float*)d_in[2];
  const float* enc_w = (const float*)d_in[3];
  const float* enc_b = (const float*)d_in[4];
  const float* ch_w = (const float*)d_in[5];
  const float* ch_b = (const float*)d_in[6];
  const float* q_w = (const float*)d_in[7];
  const float* q_b = (const float*)d_in[8];
  const float* k_w = (const float*)d_in[9];
  const float* k_b = (const float*)d_in[10];
  const float* v_w = (const float*)d_in[11];
  const float* v_b = (const float*)d_in[12];
  const float* m0w = (const float*)d_in[13];
  const float* m0b = (const float*)d_in[14];
  const float* m1w = (const float*)d_in[15];
  const float* m1b = (const float*)d_in[16];
  const float* m2w = (const float*)d_in[17];
  const float* m2b = (const float*)d_in[18];
  const float* m3w = (const float*)d_in[19];
  const float* m3b = (const float*)d_in[20];
  const float* m4w = (const float*)d_in[21];
  const float* m4b = (const float*)d_in[22];
  float* ws = (float*)d_ws;
  unsigned short* f1p = (unsigned short*)(ws + F_F1);
  unsigned short* featp = (unsigned short*)(ws + F_FEAT);
  float* featqp = ws + F_FQ;
  unsigned short* fkb = (unsigned short*)(ws + F_FKB);
  unsigned short* fvb = (unsigned short*)(ws + F_FVB);
  unsigned short* attnb = (unsigned short*)(ws + F_ATTN);
  short* w0t = (short*)(ws + F_W0T);
  short* wtb_ch = (short*)(ws + F_WTCH);
  short* wtb_q = (short*)(ws + F_WTQ);
  short* wtb_k = (short*)(ws + F_WTK);
  short* wtb_v = (short*)(ws + F_WTV);
  short* wfc1 = (short*)(ws + F_WFC1);
  short* wfc2 = (short*)(ws + F_WFC2);
  short* wfc3 = (short*)(ws + F_WFC3);
  unsigned short* h_a = (unsigned short*)(ws + F_HA);
  unsigned short* h_b = (unsigned short*)(ws + F_HB);
  float* part = ws + F_PART;
  float* outp = (float*)d_out;

  k_zero3<<<2048, 256, 0, stream>>>((float4*)ws);
  k_prep<<<5676, 256, 0, stream>>>(m0w, ch_w, q_w, k_w, v_w, m1w, m2w, m3w, w0t,
                                   wtb_ch, wtb_q, wtb_k, wtb_v, wfc1, wfc2, wfc3);
  k_conv1<<<(BB * 64 * 64 * ENC) / 256, 256, 0, stream>>>(inp, enc_w, enc_b, f1p);
  k_conv3x3m<64, false><<<dim3(3, BB * 64), 256, 0, stream>>>(f1p, wtb_ch, ch_b, featp, P1, 1);
  k_conv3x3m<192, true><<<dim3(3, BB * 64), 256, 0, stream>>>(featp, wtb_q, q_b, featqp, P1, 1);
  k_conv3x3m<192, false><<<dim3(3, BB * 64), 256, 0, stream>>>(featp, wtb_k, k_b, fkb, P3, 3);
  k_conv3x3m<192, false><<<dim3(3, BB * 64), 256, 0, stream>>>(featp, wtb_v, v_b, fvb, P3, 3);
  k_attn<<<BB * QQ, 64, 0, stream>>>(sc, featqp, fkb, attnb);
  k_l0m<<<dim3(8, 128), 256, 0, stream>>>(sc, fvb, attnb, w0t, part);
  k_l0red<<<2048, 256, 0, stream>>>(part, cell, m0w, m0b, h_a);
  k_fcm<<<dim3(4, 128), 256, 0, stream>>>(h_a, wfc1, m1b, h_b);
  k_fcm<<<dim3(4, 128), 256, 0, stream>>>(h_b, wfc2, m2b, h_a);
  k_fcm<<<dim3(4, 128), 256, 0, stream>>>(h_a, wfc3, m3b, h_b);
  k_final<<<BB * QQ, 64, 0, stream>>>(h_b, m4w, m4b, sc, inp, outp);
}